// Round 3
// baseline (189.097 us; speedup 1.0000x reference)
//
#include <hip/hip_runtime.h>
#include <hip/hip_bf16.h>
#include <stdint.h>

#define DIM 128
#define ODIM 64
#define BM 128
#define BN 64

typedef __attribute__((ext_vector_type(8))) __bf16 bf16x8;
typedef __attribute__((ext_vector_type(2))) __bf16 bf16x2;
typedef __attribute__((ext_vector_type(4))) float f32x4;
typedef __attribute__((ext_vector_type(2))) unsigned int uint32x2;
typedef __attribute__((ext_vector_type(4))) unsigned int uint32x4;

#define MFMA16(a, b, c) __builtin_amdgcn_mfma_f32_16x16x32_bf16((a), (b), (c), 0, 0, 0)

// c = log2(e) / (2*RBF_CO);  k = exp(-dist/(2*co)) = 2^(-c*dist) = 2^(-sqrt(c^2*d2))
#define RBFD 10.077141124806595
#define LOG2E 1.4426950408889634
#define C2D ((LOG2E / (2.0 * RBFD)) * (LOG2E / (2.0 * RBFD)))

__device__ __forceinline__ void async_copy16(const void* g, void* l) {
  __builtin_amdgcn_global_load_lds((const __attribute__((address_space(1))) void*)g,
                                   (__attribute__((address_space(3))) void*)l, 16, 0, 0);
}

// round-half-up bf16 pack: lo=a, hi=b  (values finite positive; +0x8000 then take hi16)
// [kept from the harness-verified round-1 kernel; do NOT swap for v_cvt_pk_bf16_f32
//  without an isolated correctness check — prime suspect in round-2's absmax failure]
__device__ __forceinline__ uint32_t pack_bf16(float a, float b) {
  uint32_t ua = __builtin_bit_cast(uint32_t, a) + 0x8000u;
  uint32_t ub = __builtin_bit_cast(uint32_t, b) + 0x8000u;
  return __builtin_amdgcn_perm(ub, ua, 0x07060302u);  // lo16=a.hi16, hi16=b.hi16
}

// ---- Merged prepass (one launch):
//  blocks [0, trainBlocks)           : train rows  -> Tb bf16 + scaled t2
//  blocks [trainBlocks, rowBlocks)   : feature rows-> Fb bf16 + scaled x2
//  blocks [rowBlocks, ...)           : weights [N][64] fp32 -> Wt [64][Npad] bf16 (LDS transpose)
__global__ void prep_all(const float* __restrict__ train, __bf16* __restrict__ Tb,
                         float* __restrict__ t2, const float* __restrict__ feat,
                         __bf16* __restrict__ Fb, float* __restrict__ x2,
                         const float* __restrict__ W, __bf16* __restrict__ Wt,
                         int Ntrain, int Npad, int nFeat,
                         int trainBlocks, int rowBlocks, float scale) {
  __shared__ float tile[64][65];
  const int b = (int)blockIdx.x;
  const int t = (int)threadIdx.x;

  if (b < rowBlocks) {
    const float* src;
    __bf16* dst;
    float* sq;
    int nValid, nPad, row0;
    float padv;
    if (b < trainBlocks) {
      src = train; dst = Tb; sq = t2; nValid = Ntrain; nPad = Npad; row0 = b * 4; padv = 1e30f;
    } else {
      src = feat; dst = Fb; sq = x2; nValid = nFeat; nPad = nFeat; row0 = (b - trainBlocks) * 4; padv = 0.0f;
    }
    int row = row0 + (t >> 6);
    int lane = t & 63;
    if (row >= nPad) return;
    float2 v = make_float2(0.0f, 0.0f);
    if (row < nValid) v = ((const float2*)src)[(size_t)row * 64 + lane];
    bf16x2 p;
    p.x = (__bf16)v.x;
    p.y = (__bf16)v.y;
    *(bf16x2*)&dst[(size_t)row * DIM + lane * 2] = p;
    float ss = v.x * v.x + v.y * v.y;
    #pragma unroll
    for (int off = 32; off > 0; off >>= 1) ss += __shfl_down(ss, off);
    if (lane == 0) sq[row] = (row < nValid) ? ss * scale : padv;
    return;
  }

  // weights transpose
  int j0 = (b - rowBlocks) * 64;
  int jr = t >> 2;
  int cg = (t & 3) * 16;
  int j = j0 + jr;
  if (j < Ntrain) {
    const float4* src = (const float4*)(W + (size_t)j * ODIM);
    #pragma unroll
    for (int q = 0; q < 4; ++q) {
      float4 u = src[(cg >> 2) + q];
      tile[jr][cg + q * 4 + 0] = u.x;
      tile[jr][cg + q * 4 + 1] = u.y;
      tile[jr][cg + q * 4 + 2] = u.z;
      tile[jr][cg + q * 4 + 3] = u.w;
    }
  } else {
    #pragma unroll
    for (int q = 0; q < 16; ++q) tile[jr][cg + q] = 0.0f;
  }
  __syncthreads();
  int v = t >> 2;
  int jc = (t & 3) * 16;
  __bf16 ob[16];
  #pragma unroll
  for (int q = 0; q < 16; ++q) ob[q] = (__bf16)tile[jc + q][v];
  __bf16* dst = Wt + (size_t)v * Npad + j0 + jc;
  *(bf16x8*)dst = *(bf16x8*)&ob[0];
  *(bf16x8*)(dst + 8) = *(bf16x8*)&ob[8];
}

// ---- Main fused kernel. Round-1 verified body; sT double-buffered (32 KB LDS),
// W fragments direct global->reg (L2-hot), 4 blocks/CU target.
template <bool ATOMIC>
__global__ __launch_bounds__(256, 4) void rbf_main(
    const __bf16* __restrict__ Fb, const __bf16* __restrict__ Tb,
    const __bf16* __restrict__ Wt, const float* __restrict__ t2g,
    const float* __restrict__ x2g, float* __restrict__ outOrPart,
    int nRows, int Npad, int nChunks, int nsplit) {
  __shared__ __bf16 sT[2][BN * DIM];  // 2 x 16 KB, XOR-swizzled 16B granules

  const int tid = threadIdx.x;
  const int wave = tid >> 6;
  const int lane = tid & 63;
  const int l16 = lane & 15;
  const int g4 = lane >> 4;

  const int ns = (int)blockIdx.x;  // 0..nsplit-1
  const int mb = (int)blockIdx.y;  // 0..15

  constexpr float KNEG2 = (float)(-2.0 * C2D);

  // F fragments (chunk-invariant): rows mb*128 + wave*32 + nf*16 + l16, 8 k each.
  bf16x8 bF[2][4];
  #pragma unroll
  for (int nf = 0; nf < 2; ++nf)
    #pragma unroll
    for (int ko = 0; ko < 4; ++ko)
      bF[nf][ko] = *(const bf16x8*)(Fb + ((size_t)(mb * BM + wave * 32 + nf * 16 + l16)) * DIM +
                                    ko * 32 + g4 * 8);

  float x2v[2];
  #pragma unroll
  for (int nf = 0; nf < 2; ++nf)
    x2v[nf] = x2g[mb * BM + wave * 32 + nf * 16 + l16];  // pre-scaled by c^2

  f32x4 zero4 = {0.0f, 0.0f, 0.0f, 0.0f};
  f32x4 oacc[2][4];
  #pragma unroll
  for (int mo = 0; mo < 2; ++mo)
    #pragma unroll
    for (int vi = 0; vi < 4; ++vi) oacc[mo][vi] = zero4;

  // Stage T chunk c into buffer bsel. LDS dest is wave-uniform base + lane*16;
  // swizzle on the global source: LDS granule (row,g) holds global granule g^(row&15).
  auto stage = [&](int bsel, int c) {
    const char* gT = (const char*)Tb + (size_t)c * (BN * DIM * 2);
    char* lT = (char*)&sT[bsel][0];
    #pragma unroll
    for (int i = 0; i < 4; ++i) {
      int off = i * 4096 + wave * 1024;
      int loff = off + lane * 16;
      int row = loff >> 8;
      int gran = (loff >> 4) & 15;
      async_copy16(gT + row * 256 + ((gran ^ (row & 15)) << 4), lT + off);
    }
  };

  stage(0, ns);
  int buf = 0;

  for (int c = ns; c < nChunks; c += nsplit) {
    const int n0 = c * BN;
    // Single barrier per chunk: drains own staging vmcnt -> sT[buf] ready; also
    // guarantees all waves finished reading buf^1, so we can re-stage it now.
    __syncthreads();

    // t2 for this chunk (global, L2-hot), issued before the stage so waiting on
    // them does not drain the staging queue.
    f32x4 t2v[4];
    #pragma unroll
    for (int mt = 0; mt < 4; ++mt)
      t2v[mt] = *(const f32x4*)(t2g + n0 + mt * 16 + g4 * 4);

    int cn = c + nsplit;
    if (cn < nChunks) stage(buf ^ 1, cn);  // overlaps with all compute below

    // S^T = T · F^T : tiles m = train (4), n = feat (2 per wave)
    f32x4 sacc[4][2];
    #pragma unroll
    for (int mt = 0; mt < 4; ++mt)
      #pragma unroll
      for (int nf = 0; nf < 2; ++nf) sacc[mt][nf] = zero4;

    #pragma unroll
    for (int ko = 0; ko < 4; ++ko) {
      bf16x8 a[4];
      #pragma unroll
      for (int mt = 0; mt < 4; ++mt) {
        int row = mt * 16 + l16;
        int slot = (ko * 4 + g4) ^ l16;
        a[mt] = *(const bf16x8*)((const char*)&sT[buf][0] + row * 256 + (slot << 4));
      }
      #pragma unroll
      for (int mt = 0; mt < 4; ++mt)
        #pragma unroll
        for (int nf = 0; nf < 2; ++nf)
          sacc[mt][nf] = MFMA16(a[mt], bF[nf][ko], sacc[mt][nf]);
    }

    // elementwise: d2' = x2' + t2' - 2c^2*s ; k = 2^(-sqrt(d2')) ; pack to bf16 dwords
    uint32_t plo[4][2], phi[4][2];
    #pragma unroll
    for (int mt = 0; mt < 4; ++mt) {
      #pragma unroll
      for (int nf = 0; nf < 2; ++nf) {
        f32x4 s = sacc[mt][nf];
        float kv[4];
        #pragma unroll
        for (int r = 0; r < 4; ++r) {
          float d2 = __builtin_fmaf(KNEG2, s[r], t2v[mt][r] + x2v[nf]);
          d2 = fmaxf(d2, 0.0f);
          kv[r] = __builtin_amdgcn_exp2f(-__builtin_amdgcn_sqrtf(d2));
        }
        plo[mt][nf] = pack_bf16(kv[0], kv[1]);  // k offsets g4*4 + {0,1}
        phi[mt][nf] = pack_bf16(kv[2], kv[3]);  // k offsets g4*4 + {2,3}
      }
    }

    // W fragments direct from global (B-frag: lane holds W[k][out=vi*16+l16],
    // k = n0 + ko2*32 + g4*8 + j). Element-identical to round-1's sW path.
    bf16x8 w[2][4];
    #pragma unroll
    for (int ko2 = 0; ko2 < 2; ++ko2)
      #pragma unroll
      for (int vi = 0; vi < 4; ++vi)
        w[ko2][vi] = *(const bf16x8*)(Wt + (size_t)(vi * 16 + l16) * Npad + n0 + ko2 * 32 + g4 * 8);

    // O += P · W, P redistributed in-register:
    //   swap32(P_m0, P_m1) -> [m0@g0, m0@g1, m1@g0, m1@g1] / [m0@g2, ...]
    //   swap16(.)          -> frag dword pos0 / pos1
    #pragma unroll
    for (int ko2 = 0; ko2 < 2; ++ko2) {
      #pragma unroll
      for (int nf = 0; nf < 2; ++nf) {
        uint32x2 rA = __builtin_amdgcn_permlane32_swap(plo[2 * ko2][nf], plo[2 * ko2 + 1][nf],
                                                       false, false);
        uint32x2 rB = __builtin_amdgcn_permlane16_swap(rA[0], rA[1], false, false);
        uint32x2 rC = __builtin_amdgcn_permlane32_swap(phi[2 * ko2][nf], phi[2 * ko2 + 1][nf],
                                                       false, false);
        uint32x2 rD = __builtin_amdgcn_permlane16_swap(rC[0], rC[1], false, false);
        uint32x4 pd = {rB[0], rD[0], rB[1], rD[1]};
        bf16x8 p = __builtin_bit_cast(bf16x8, pd);
        #pragma unroll
        for (int vi = 0; vi < 4; ++vi)
          oacc[nf][vi] = MFMA16(p, w[ko2][vi], oacc[nf][vi]);
      }
    }

    buf ^= 1;
  }

  if (ATOMIC) {
    float* out = outOrPart;
    #pragma unroll
    for (int mo = 0; mo < 2; ++mo)
      #pragma unroll
      for (int vi = 0; vi < 4; ++vi)
        #pragma unroll
        for (int r = 0; r < 4; ++r) {
          int row = mb * BM + wave * 32 + mo * 16 + g4 * 4 + r;
          int col = vi * 16 + l16;
          atomicAdd(&out[(size_t)row * ODIM + col], oacc[mo][vi][r]);
        }
  } else {
    float* dst = outOrPart + (size_t)ns * (size_t)nRows * ODIM;
    #pragma unroll
    for (int mo = 0; mo < 2; ++mo)
      #pragma unroll
      for (int vi = 0; vi < 4; ++vi)
        #pragma unroll
        for (int r = 0; r < 4; ++r) {
          int row = mb * BM + wave * 32 + mo * 16 + g4 * 4 + r;
          int col = vi * 16 + l16;
          dst[(size_t)row * ODIM + col] = oacc[mo][vi][r];
        }
  }
}

__global__ void reduce_parts(const float4* __restrict__ part, float4* __restrict__ out,
                             int total4, int nsplit) {
  int i = (int)blockIdx.x * blockDim.x + threadIdx.x;
  if (i >= total4) return;
  float4 s = make_float4(0.0f, 0.0f, 0.0f, 0.0f);
  for (int sp = 0; sp < nsplit; ++sp) {
    float4 v = part[(size_t)sp * total4 + i];
    s.x += v.x; s.y += v.y; s.z += v.z; s.w += v.w;
  }
  out[i] = s;
}

extern "C" void kernel_launch(void* const* d_in, const int* in_sizes, int n_in,
                              void* d_out, int out_size, void* d_ws, size_t ws_size,
                              hipStream_t stream) {
  (void)n_in;
  const float* features = (const float*)d_in[0];
  const float* train = (const float*)d_in[1];
  const float* weights = (const float*)d_in[2];
  float* out = (float*)d_out;

  const int n = in_sizes[0] / DIM;              // 2048
  const int N = in_sizes[1] / DIM;              // 50000
  const int Npad = ((N + 63) / 64) * 64;        // 50048
  const int nChunks = Npad / 64;                // 782

  size_t off = 0;
  auto alloc = [&](size_t bytes) {
    size_t o = off;
    off = (off + bytes + 255) & ~(size_t)255;
    return o;
  };
  size_t oT = alloc((size_t)Npad * DIM * 2);
  size_t oW = alloc((size_t)ODIM * Npad * 2);
  size_t oF = alloc((size_t)n * DIM * 2);
  size_t ot2 = alloc((size_t)Npad * 4);
  size_t ox2 = alloc((size_t)n * 4);
  size_t oPart = alloc(0);                       // partials start here
  size_t fixed = off;

  // largest nsplit whose partial buffer fits the workspace:
  // 64 -> grid 1024 = exactly 4 blocks/CU (32 KB LDS, <=128 VGPR); fallback 48.
  int nsplit = 64;
  size_t partBytes = (size_t)nsplit * n * ODIM * 4;
  bool haveWs = ws_size >= fixed + partBytes;
  if (!haveWs) {
    nsplit = 48;
    partBytes = (size_t)nsplit * n * ODIM * 4;
    haveWs = ws_size >= fixed + partBytes;
  }

  char* ws = (char*)d_ws;
  __bf16* Tb = (__bf16*)(ws + oT);
  __bf16* Wt = (__bf16*)(ws + oW);
  __bf16* Fb = (__bf16*)(ws + oF);
  float* t2 = (float*)(ws + ot2);
  float* x2 = (float*)(ws + ox2);

  const float scale = (float)C2D;
  const int trainBlocks = Npad / 4;
  const int rowBlocks = trainBlocks + n / 4;
  const int wBlocks = Npad / 64;
  prep_all<<<rowBlocks + wBlocks, 256, 0, stream>>>(train, Tb, t2, features, Fb, x2,
                                                    weights, Wt, N, Npad, n,
                                                    trainBlocks, rowBlocks, scale);

  const int mBlocks = n / BM;                    // 16
  dim3 grid((unsigned)(haveWs ? nsplit : 64), (unsigned)mBlocks);

  if (haveWs) {
    float* part = (float*)(ws + oPart);
    rbf_main<false><<<grid, 256, 0, stream>>>(Fb, Tb, Wt, t2, x2, part, n, Npad, nChunks, nsplit);
    int total4 = n * ODIM / 4;
    reduce_parts<<<(total4 + 255) / 256, 256, 0, stream>>>((const float4*)part, (float4*)out,
                                                           total4, nsplit);
  } else {
    hipMemsetAsync(d_out, 0, (size_t)out_size * sizeof(float), stream);
    rbf_main<true><<<grid, 256, 0, stream>>>(Fb, Tb, Wt, t2, x2, out, n, Npad, nChunks, 64);
  }
}

// Round 4
// 146.629 us; speedup vs baseline: 1.2896x; 1.2896x over previous
//
#include <hip/hip_runtime.h>
#include <hip/hip_bf16.h>
#include <stdint.h>

#define DIM 128
#define ODIM 64
#define BM 128
#define BN 64
#define NSPLIT 48

typedef __attribute__((ext_vector_type(8))) __bf16 bf16x8;
typedef __attribute__((ext_vector_type(2))) __bf16 bf16x2;
typedef __attribute__((ext_vector_type(4))) float f32x4;

#define MFMA16(a, b, c) __builtin_amdgcn_mfma_f32_16x16x32_bf16((a), (b), (c), 0, 0, 0)

// c = log2(e) / (2*RBF_CO);  k = exp(-dist/(2*co)) = 2^(-c*dist) = 2^(-sqrt(c^2*d2))
// d2' = c^2*d2 = c^2*x2 + c^2*t2 + (-2c^2*t)·x  -> MFMA with A = -2c^2*t (pre-scaled
// in prepass), C initialized to c^2*(t2 + x2). No per-element fma/scale needed.
#define RBFD 10.077141124806595
#define LOG2E 1.4426950408889634
#define C2D ((LOG2E / (2.0 * RBFD)) * (LOG2E / (2.0 * RBFD)))

__device__ __forceinline__ void async_copy16(const void* g, void* l) {
  __builtin_amdgcn_global_load_lds((const __attribute__((address_space(1))) void*)g,
                                   (__attribute__((address_space(3))) void*)l, 16, 0, 0);
}

// round-half-up bf16 pack: lo=a, hi=b  (values finite positive; +0x8000 then take hi16)
// [harness-verified; do NOT swap for v_cvt_pk_bf16_f32 without isolated verification]
__device__ __forceinline__ uint32_t pack_bf16(float a, float b) {
  uint32_t ua = __builtin_bit_cast(uint32_t, a) + 0x8000u;
  uint32_t ub = __builtin_bit_cast(uint32_t, b) + 0x8000u;
  return __builtin_amdgcn_perm(ub, ua, 0x07060302u);  // lo16=a.hi16, hi16=b.hi16
}

// ---- Merged prepass (one launch):
//  blocks [0, trainBlocks)           : train rows  -> Tb = bf16(-2c^2 * t) + t2 = c^2*sum(t^2)
//  blocks [trainBlocks, rowBlocks)   : feature rows-> Fb = bf16(x)         + x2 = c^2*sum(x^2)
//  blocks [rowBlocks, ...)           : weights [N][64] fp32 -> Wt [64][Npad] bf16 (LDS transpose)
__global__ void prep_all(const float* __restrict__ train, __bf16* __restrict__ Tb,
                         float* __restrict__ t2, const float* __restrict__ feat,
                         __bf16* __restrict__ Fb, float* __restrict__ x2,
                         const float* __restrict__ W, __bf16* __restrict__ Wt,
                         int Ntrain, int Npad, int nFeat,
                         int trainBlocks, int rowBlocks, float scale, float tScale) {
  __shared__ float tile[64][65];
  const int b = (int)blockIdx.x;
  const int t = (int)threadIdx.x;

  if (b < rowBlocks) {
    const float* src;
    __bf16* dst;
    float* sq;
    int nValid, nPad, row0;
    float padv, rowScale;
    if (b < trainBlocks) {
      src = train; dst = Tb; sq = t2; nValid = Ntrain; nPad = Npad; row0 = b * 4;
      padv = 1e30f; rowScale = tScale;  // -2*c^2
    } else {
      src = feat; dst = Fb; sq = x2; nValid = nFeat; nPad = nFeat; row0 = (b - trainBlocks) * 4;
      padv = 0.0f; rowScale = 1.0f;
    }
    int row = row0 + (t >> 6);
    int lane = t & 63;
    if (row >= nPad) return;
    float2 v = make_float2(0.0f, 0.0f);
    if (row < nValid) v = ((const float2*)src)[(size_t)row * 64 + lane];
    float ss = v.x * v.x + v.y * v.y;   // from RAW values (before rowScale)
    bf16x2 p;
    p.x = (__bf16)(v.x * rowScale);
    p.y = (__bf16)(v.y * rowScale);
    *(bf16x2*)&dst[(size_t)row * DIM + lane * 2] = p;
    #pragma unroll
    for (int off = 32; off > 0; off >>= 1) ss += __shfl_down(ss, off);
    if (lane == 0) sq[row] = (row < nValid) ? ss * scale : padv;
    return;
  }

  // weights transpose
  int j0 = (b - rowBlocks) * 64;
  int jr = t >> 2;
  int cg = (t & 3) * 16;
  int j = j0 + jr;
  if (j < Ntrain) {
    const float4* src = (const float4*)(W + (size_t)j * ODIM);
    #pragma unroll
    for (int q = 0; q < 4; ++q) {
      float4 u = src[(cg >> 2) + q];
      tile[jr][cg + q * 4 + 0] = u.x;
      tile[jr][cg + q * 4 + 1] = u.y;
      tile[jr][cg + q * 4 + 2] = u.z;
      tile[jr][cg + q * 4 + 3] = u.w;
    }
  } else {
    #pragma unroll
    for (int q = 0; q < 16; ++q) tile[jr][cg + q] = 0.0f;
  }
  __syncthreads();
  int v = t >> 2;
  int jc = (t & 3) * 16;
  __bf16 ob[16];
  #pragma unroll
  for (int q = 0; q < 16; ++q) ob[q] = (__bf16)tile[jc + q][v];
  __bf16* dst = Wt + (size_t)v * Npad + j0 + jc;
  *(bf16x8*)dst = *(bf16x8*)&ob[0];
  *(bf16x8*)(dst + 8) = *(bf16x8*)&ob[8];
}

// ---- Main fused kernel (S^T formulation). R0 structure: single-buffered sT/sW,
// two barriers/chunk, wave-private sP strip (now XOR-swizzled, unpadded 128B rows).
// S-accumulator initialized to c^2*(t2+x2) so sacc emerges as d2' directly.
template <bool ATOMIC>
__global__ __launch_bounds__(256, 3) void rbf_main(
    const __bf16* __restrict__ Fb, const __bf16* __restrict__ Tb,
    const __bf16* __restrict__ Wt, const float* __restrict__ t2g,
    const float* __restrict__ x2g, float* __restrict__ outOrPart,
    int nRows, int Npad, int nChunks) {
  __shared__ __bf16 sT[BN * DIM];   // 16 KB, XOR-swizzled 16B granules
  __shared__ __bf16 sW[ODIM * BN];  // 8 KB, XOR-swizzled 16B granules
  __shared__ __bf16 sP[BM * 64];    // 16 KB, wave-private 32-row strips, swizzled granules

  const int tid = threadIdx.x;
  const int wave = tid >> 6;
  const int lane = tid & 63;
  const int l16 = lane & 15;
  const int g4 = lane >> 4;

  const int ns = (int)blockIdx.x;  // 0..NSPLIT-1
  const int mb = (int)blockIdx.y;  // 0..15

  // F fragments (chunk-invariant): rows mb*128 + wave*32 + nf*16 + l16, 8 k each.
  bf16x8 bF[2][4];
  #pragma unroll
  for (int nf = 0; nf < 2; ++nf)
    #pragma unroll
    for (int ko = 0; ko < 4; ++ko)
      bF[nf][ko] = *(const bf16x8*)(Fb + ((size_t)(mb * BM + wave * 32 + nf * 16 + l16)) * DIM +
                                    ko * 32 + g4 * 8);

  float x2v[2];
  #pragma unroll
  for (int nf = 0; nf < 2; ++nf)
    x2v[nf] = x2g[mb * BM + wave * 32 + nf * 16 + l16];  // pre-scaled by c^2

  f32x4 zero4 = {0.0f, 0.0f, 0.0f, 0.0f};
  f32x4 oacc[2][4];
  #pragma unroll
  for (int mo = 0; mo < 2; ++mo)
    #pragma unroll
    for (int vi = 0; vi < 4; ++vi) oacc[mo][vi] = zero4;

  for (int c = ns; c < nChunks; c += NSPLIT) {
    const int n0 = c * BN;

    // Stage T chunk [64][128] bf16. LDS granule (row,g) holds global granule g^(row&15).
    {
      const char* gT = (const char*)Tb + (size_t)n0 * 256;
      #pragma unroll
      for (int i = 0; i < 4; ++i) {
        int off = i * 4096 + wave * 1024;  // wave-uniform LDS base
        int loff = off + lane * 16;
        int row = loff >> 8;
        int gran = (loff >> 4) & 15;
        async_copy16(gT + row * 256 + ((gran ^ (row & 15)) << 4), (char*)sT + off);
      }
    }
    // Stage W chunk: sW[v][0..63] = Wt[v][n0..n0+63]; granule g holds global g^(v&7).
    {
      #pragma unroll
      for (int i = 0; i < 2; ++i) {
        int off = i * 4096 + wave * 1024;
        int loff = off + lane * 16;
        int v = loff >> 7;
        int gran = (loff >> 4) & 7;
        const char* gW = (const char*)Wt + ((size_t)v * Npad + n0) * 2 + ((gran ^ (v & 7)) << 4);
        async_copy16(gW, (char*)sW + off);
      }
    }
    // t2 for this chunk direct from global (L2-hot); drained by the same barrier.
    f32x4 t2v[4];
    #pragma unroll
    for (int mt = 0; mt < 4; ++mt)
      t2v[mt] = *(const f32x4*)(t2g + n0 + mt * 16 + g4 * 4);

    __syncthreads();

    // S^T = (-2c^2*T) · F^T + (t2' + x2') : sacc directly holds d2'.
    f32x4 sacc[4][2];
    #pragma unroll
    for (int mt = 0; mt < 4; ++mt)
      #pragma unroll
      for (int nf = 0; nf < 2; ++nf)
        #pragma unroll
        for (int r = 0; r < 4; ++r) sacc[mt][nf][r] = t2v[mt][r] + x2v[nf];

    #pragma unroll
    for (int ko = 0; ko < 4; ++ko) {
      bf16x8 a[4];
      #pragma unroll
      for (int mt = 0; mt < 4; ++mt) {
        int row = mt * 16 + l16;
        int slot = (ko * 4 + g4) ^ l16;
        a[mt] = *(const bf16x8*)((const char*)sT + row * 256 + (slot << 4));
      }
      #pragma unroll
      for (int mt = 0; mt < 4; ++mt)
        #pragma unroll
        for (int nf = 0; nf < 2; ++nf)
          sacc[mt][nf] = MFMA16(a[mt], bF[nf][ko], sacc[mt][nf]);
    }

    // elementwise: k = 2^(-sqrt(max(d2',0))) ; pack 4 bf16 -> swizzled b64 write.
    // sP row = feat (wave-private strip), col k = train offset; granule XOR (l16&7).
    #pragma unroll
    for (int mt = 0; mt < 4; ++mt) {
      #pragma unroll
      for (int nf = 0; nf < 2; ++nf) {
        float kv[4];
        #pragma unroll
        for (int r = 0; r < 4; ++r) {
          float d2 = fmaxf(sacc[mt][nf][r], 0.0f);
          kv[r] = __builtin_amdgcn_exp2f(-__builtin_amdgcn_sqrtf(d2));
        }
        uint32_t lo = pack_bf16(kv[0], kv[1]);
        uint32_t hi = pack_bf16(kv[2], kv[3]);
        int prow = wave * 32 + nf * 16 + l16;
        int gran = (2 * mt + (g4 >> 1)) ^ (l16 & 7);
        uint2* dst = (uint2*)((char*)sP + prow * 128 + (gran << 4) + (g4 & 1) * 8);
        *dst = make_uint2(lo, hi);
      }
    }
    // NOTE: no barrier — each wave's sP strip is written and read only by itself
    // (compiler inserts lgkmcnt waits for the LDS dependency).

    // O += P · W
    #pragma unroll
    for (int ko2 = 0; ko2 < 2; ++ko2) {
      bf16x8 p[2];
      #pragma unroll
      for (int mo = 0; mo < 2; ++mo) {
        int prow = wave * 32 + mo * 16 + l16;
        int gran = (ko2 * 4 + g4) ^ (l16 & 7);
        p[mo] = *(const bf16x8*)((const char*)sP + prow * 128 + (gran << 4));
      }
      bf16x8 w[4];
      #pragma unroll
      for (int vi = 0; vi < 4; ++vi) {
        int v = vi * 16 + l16;
        int slot = (ko2 * 4 + g4) ^ (l16 & 7);
        w[vi] = *(const bf16x8*)((const char*)sW + v * 128 + (slot << 4));
      }
      #pragma unroll
      for (int mo = 0; mo < 2; ++mo)
        #pragma unroll
        for (int vi = 0; vi < 4; ++vi)
          oacc[mo][vi] = MFMA16(p[mo], w[vi], oacc[mo][vi]);
    }
    __syncthreads();  // protect sT/sW from next chunk's staging
  }

  if (ATOMIC) {
    float* out = outOrPart;
    #pragma unroll
    for (int mo = 0; mo < 2; ++mo)
      #pragma unroll
      for (int vi = 0; vi < 4; ++vi)
        #pragma unroll
        for (int r = 0; r < 4; ++r) {
          int row = mb * BM + wave * 32 + mo * 16 + g4 * 4 + r;
          int col = vi * 16 + l16;
          atomicAdd(&out[(size_t)row * ODIM + col], oacc[mo][vi][r]);
        }
  } else {
    float* dst = outOrPart + (size_t)ns * (size_t)nRows * ODIM;
    #pragma unroll
    for (int mo = 0; mo < 2; ++mo)
      #pragma unroll
      for (int vi = 0; vi < 4; ++vi)
        #pragma unroll
        for (int r = 0; r < 4; ++r) {
          int row = mb * BM + wave * 32 + mo * 16 + g4 * 4 + r;
          int col = vi * 16 + l16;
          dst[(size_t)row * ODIM + col] = oacc[mo][vi][r];
        }
  }
}

__global__ void reduce_parts(const float4* __restrict__ part, float4* __restrict__ out,
                             int total4) {
  int i = (int)blockIdx.x * blockDim.x + threadIdx.x;
  if (i >= total4) return;
  float4 s = make_float4(0.0f, 0.0f, 0.0f, 0.0f);
  #pragma unroll
  for (int sp = 0; sp < NSPLIT; ++sp) {
    float4 v = part[(size_t)sp * total4 + i];
    s.x += v.x; s.y += v.y; s.z += v.z; s.w += v.w;
  }
  out[i] = s;
}

extern "C" void kernel_launch(void* const* d_in, const int* in_sizes, int n_in,
                              void* d_out, int out_size, void* d_ws, size_t ws_size,
                              hipStream_t stream) {
  (void)n_in;
  const float* features = (const float*)d_in[0];
  const float* train = (const float*)d_in[1];
  const float* weights = (const float*)d_in[2];
  float* out = (float*)d_out;

  const int n = in_sizes[0] / DIM;              // 2048
  const int N = in_sizes[1] / DIM;              // 50000
  const int Npad = ((N + 63) / 64) * 64;        // 50048
  const int nChunks = Npad / 64;                // 782

  size_t off = 0;
  auto alloc = [&](size_t bytes) {
    size_t o = off;
    off = (off + bytes + 255) & ~(size_t)255;
    return o;
  };
  size_t oT = alloc((size_t)Npad * DIM * 2);
  size_t oW = alloc((size_t)ODIM * Npad * 2);
  size_t oF = alloc((size_t)n * DIM * 2);
  size_t ot2 = alloc((size_t)Npad * 4);
  size_t ox2 = alloc((size_t)n * 4);
  size_t oPart = alloc((size_t)NSPLIT * n * ODIM * 4);
  size_t needFull = off;

  char* ws = (char*)d_ws;
  __bf16* Tb = (__bf16*)(ws + oT);
  __bf16* Wt = (__bf16*)(ws + oW);
  __bf16* Fb = (__bf16*)(ws + oF);
  float* t2 = (float*)(ws + ot2);
  float* x2 = (float*)(ws + ox2);

  const float scale = (float)C2D;
  const float tScale = (float)(-2.0 * C2D);
  const int trainBlocks = Npad / 4;
  const int rowBlocks = trainBlocks + n / 4;
  const int wBlocks = Npad / 64;
  prep_all<<<rowBlocks + wBlocks, 256, 0, stream>>>(train, Tb, t2, features, Fb, x2,
                                                    weights, Wt, N, Npad, n,
                                                    trainBlocks, rowBlocks, scale, tScale);

  const int mBlocks = n / BM;                    // 16
  dim3 grid(NSPLIT, mBlocks);                    // 768 blocks = 3/CU

  if (ws_size >= needFull) {
    float* part = (float*)(ws + oPart);
    rbf_main<false><<<grid, 256, 0, stream>>>(Fb, Tb, Wt, t2, x2, part, n, Npad, nChunks);
    int total4 = n * ODIM / 4;
    reduce_parts<<<(total4 + 255) / 256, 256, 0, stream>>>((const float4*)part, (float4*)out,
                                                           total4);
  } else {
    hipMemsetAsync(d_out, 0, (size_t)out_size * sizeof(float), stream);
    rbf_main<true><<<grid, 256, 0, stream>>>(Fb, Tb, Wt, t2, x2, out, n, Npad, nChunks);
  }
}